// Round 7
// baseline (394.728 us; speedup 1.0000x reference)
//
#include <hip/hip_runtime.h>

#define D 128
#define NUSERS 100000
#define NITEMS 50000
#define NNODES 150000
#define NEDGES 3200000
#define NSEL 2048
#define NBKT 586                 // ceil(150000 / 256) row-buckets of 256 rows
#define PBLK 256                 // partition blocks
#define EPB (NEDGES / PBLK)      // 12500 edges per partition block
#define MATN (NBKT * PBLK)       // 150016 (bucket-major count matrix)
#define MB ((MATN + 255) / 256)  // 586 scan blocks

typedef unsigned int uint_t;
typedef unsigned short ushort_t;

__device__ inline uint_t bf16_rne(float f) {
    uint_t x = __float_as_uint(f);
    return (x + 0x7FFFu + ((x >> 16) & 1u)) >> 16;
}

// cur(bf16) = concat(user_emb, item_emb); each thread converts 8 floats -> uint4
__global__ void k_init_bf16(const float4* __restrict__ u4, const float4* __restrict__ i4,
                            uint4* __restrict__ cur) {
    size_t total8 = (size_t)NNODES * D / 8;
    size_t ub8 = (size_t)NUSERS * D / 8;
    size_t stride = (size_t)gridDim.x * blockDim.x;
    for (size_t i = (size_t)blockIdx.x * blockDim.x + threadIdx.x; i < total8; i += stride) {
        const float4* src = (i < ub8) ? &u4[2 * i] : &i4[2 * (i - ub8)];
        float4 a = src[0], b = src[1];
        uint4 o;
        o.x = (bf16_rne(a.y) << 16) | bf16_rne(a.x);
        o.y = (bf16_rne(a.w) << 16) | bf16_rne(a.z);
        o.z = (bf16_rne(b.y) << 16) | bf16_rne(b.x);
        o.w = (bf16_rne(b.w) << 16) | bf16_rne(b.z);
        cur[i] = o;
    }
}

// ---- generic block exclusive scan helper ----
__device__ inline int block_excl_scan(int v, int* lds, int nw) {
    int lane = threadIdx.x & 63;
    int wid = (int)(threadIdx.x >> 6);
    int x = v;
    #pragma unroll
    for (int off = 1; off < 64; off <<= 1) {
        int y = __shfl_up(x, off);
        if (lane >= off) x += y;
    }
    if (lane == 63) lds[wid] = x;
    __syncthreads();
    if (wid == 0) {
        int s = (lane < nw) ? lds[lane] : 0;
        #pragma unroll
        for (int off = 1; off < 16; off <<= 1) {
            int y = __shfl_up(s, off);
            if (lane >= off) s += y;
        }
        if (lane < nw) lds[lane] = s;
    }
    __syncthreads();
    int waveoff = (wid == 0) ? 0 : lds[wid - 1];
    return waveoff + x - v;
}

// P1: per-block LDS bucket histogram -> mat[bucket][block]  (no global atomics)
__global__ void k_p1(const int* __restrict__ row, int* __restrict__ mat) {
    __shared__ int h[NBKT];
    for (int i = threadIdx.x; i < NBKT; i += 256) h[i] = 0;
    __syncthreads();
    int beg = blockIdx.x * EPB, end = beg + EPB;
    for (int e = beg + threadIdx.x; e < end; e += 256)
        atomicAdd(&h[row[e] >> 8], 1);
    __syncthreads();
    for (int i = threadIdx.x; i < NBKT; i += 256)
        mat[i * PBLK + blockIdx.x] = h[i];
}

__global__ void k_blocksum(const int* __restrict__ src, int* __restrict__ bsums, int n) {
    int i = blockIdx.x * 256 + threadIdx.x;
    int v = (i < n) ? src[i] : 0;
    #pragma unroll
    for (int off = 32; off; off >>= 1) v += __shfl_down(v, off);
    __shared__ int lds[4];
    int lane = threadIdx.x & 63, wid = (int)(threadIdx.x >> 6);
    if (lane == 0) lds[wid] = v;
    __syncthreads();
    if (threadIdx.x == 0) bsums[blockIdx.x] = lds[0] + lds[1] + lds[2] + lds[3];
}

__global__ void k_scanbsums(int* __restrict__ bsums, int nb) {
    __shared__ int lds[16];
    int t = threadIdx.x;
    int v = (t < nb) ? bsums[t] : 0;
    int ex = block_excl_scan(v, lds, 16);
    if (t < nb) bsums[t] = ex;
}

// in-place exclusive scan finalize: mat[i] = bsums[blk] + local exclusive
__global__ void k_scan_inplace(int* __restrict__ mat, const int* __restrict__ bsums, int n) {
    __shared__ int lds[4];
    int i = blockIdx.x * 256 + threadIdx.x;
    int v = (i < n) ? mat[i] : 0;
    int ex = block_excl_scan(v, lds, 4);
    if (i < n) mat[i] = bsums[blockIdx.x] + ex;
}

// P2: partition scatter using LDS cursors seeded from scanned mat (no global atomics)
__global__ void k_p2(const int* __restrict__ row, const int* __restrict__ col,
                     const float* __restrict__ val, const int* __restrict__ mat,
                     int2* __restrict__ tmp) {
    __shared__ int cur[NBKT];
    for (int i = threadIdx.x; i < NBKT; i += 256)
        cur[i] = mat[i * PBLK + blockIdx.x];
    __syncthreads();
    int beg = blockIdx.x * EPB, end = beg + EPB;
    for (int e = beg + threadIdx.x; e < end; e += 256) {
        int r = row[e];
        int b = r >> 8;
        int pos = atomicAdd(&cur[b], 1);
        int2 rc;
        rc.x = ((r & 255) << 24) | col[e];   // col < 2^24
        rc.y = __float_as_int(val[e]);
        tmp[pos] = rc;
    }
}

// P3: per-bucket exact CSR: 256-row LDS histogram + scan -> row_start + final records
__global__ void k_p3(const int2* __restrict__ tmp, const int* __restrict__ mat,
                     int2* __restrict__ recs, int* __restrict__ row_start) {
    int b = blockIdx.x;
    int beg = mat[b * PBLK];
    int end = (b + 1 < NBKT) ? mat[(b + 1) * PBLK] : NEDGES;
    __shared__ int h[256];
    __shared__ int lds[4];
    h[threadIdx.x] = 0;
    __syncthreads();
    for (int e = beg + threadIdx.x; e < end; e += 256)
        atomicAdd(&h[((uint_t)tmp[e].x) >> 24], 1);
    __syncthreads();
    int ex = block_excl_scan(h[threadIdx.x], lds, 4);
    int rowid = b * 256 + threadIdx.x;
    if (rowid < NNODES) row_start[rowid] = beg + ex;
    if (b == NBKT - 1 && threadIdx.x == 0) row_start[NNODES] = NEDGES;
    h[threadIdx.x] = ex;       // becomes the per-row LDS cursor
    __syncthreads();
    for (int e = beg + threadIdx.x; e < end; e += 256) {
        int2 rc = tmp[e];
        int lr = ((uint_t)rc.x) >> 24;
        int pos = beg + atomicAdd(&h[lr], 1);
        int2 o;
        o.x = rc.x & 0xFFFFFF;
        o.y = rc.y;
        recs[pos] = o;
    }
}

// CSR SpMM on bf16 table: one wave per row. Lanes cooperatively vector-load
// 64 edge records, then broadcast via readlane (register-only) so the 256B
// row gathers issue back-to-back with no interleaved memory dependency.
__global__ void k_spmm_csr(const uint_t* __restrict__ emb, uint_t* __restrict__ outp,
                           const int* __restrict__ row_start,
                           const int2* __restrict__ recs) {
    int lane = threadIdx.x & 63;
    int w = (int)((blockIdx.x * blockDim.x + threadIdx.x) >> 6);
    if (w >= NNODES) return;
    int beg = __builtin_amdgcn_readfirstlane(row_start[w]);
    int end = __builtin_amdgcn_readfirstlane(row_start[w + 1]);
    float ax = 0.f, ay = 0.f;
    for (int k0 = beg; k0 < end; k0 += 64) {
        int m = end - k0;             // >0; usually the whole row (deg ~21)
        if (m > 64) m = 64;
        int2 rec = recs[k0 + lane];   // coalesced; harmless overread within ws
        int rx = rec.x, ry = rec.y;
        int k = 0;
        for (; k + 3 < m; k += 4) {
            int c0 = __builtin_amdgcn_readlane(rx, k);
            int c1 = __builtin_amdgcn_readlane(rx, k + 1);
            int c2 = __builtin_amdgcn_readlane(rx, k + 2);
            int c3 = __builtin_amdgcn_readlane(rx, k + 3);
            float v0 = __int_as_float(__builtin_amdgcn_readlane(ry, k));
            float v1 = __int_as_float(__builtin_amdgcn_readlane(ry, k + 1));
            float v2 = __int_as_float(__builtin_amdgcn_readlane(ry, k + 2));
            float v3 = __int_as_float(__builtin_amdgcn_readlane(ry, k + 3));
            uint_t g0 = emb[(size_t)c0 * 64 + lane];
            uint_t g1 = emb[(size_t)c1 * 64 + lane];
            uint_t g2 = emb[(size_t)c2 * 64 + lane];
            uint_t g3 = emb[(size_t)c3 * 64 + lane];
            ax += v0 * __uint_as_float(g0 << 16) + v1 * __uint_as_float(g1 << 16)
                + v2 * __uint_as_float(g2 << 16) + v3 * __uint_as_float(g3 << 16);
            ay += v0 * __uint_as_float(g0 & 0xFFFF0000u) + v1 * __uint_as_float(g1 & 0xFFFF0000u)
                + v2 * __uint_as_float(g2 & 0xFFFF0000u) + v3 * __uint_as_float(g3 & 0xFFFF0000u);
        }
        for (; k < m; ++k) {
            int c = __builtin_amdgcn_readlane(rx, k);
            float v = __int_as_float(__builtin_amdgcn_readlane(ry, k));
            uint_t g = emb[(size_t)c * 64 + lane];
            ax += v * __uint_as_float(g << 16);
            ay += v * __uint_as_float(g & 0xFFFF0000u);
        }
    }
    outp[(size_t)w * 64 + lane] = (bf16_rne(ay) << 16) | bf16_rne(ax);
}

// layer-3 SpMM at selected rows only, fused with acc += emb[node]
__global__ void k_spmm_sel(const uint_t* __restrict__ emb,
                           const int* __restrict__ users, const int* __restrict__ items,
                           const int* __restrict__ row_start,
                           const int2* __restrict__ recs,
                           float* __restrict__ acc) {
    int lane = threadIdx.x & 63;
    int w = (int)((blockIdx.x * blockDim.x + threadIdx.x) >> 6);
    if (w >= 2 * NSEL) return;
    int node = (w < NSEL) ? users[w] : NUSERS + items[w - NSEL];
    int beg = __builtin_amdgcn_readfirstlane(row_start[node]);
    int end = __builtin_amdgcn_readfirstlane(row_start[node + 1]);
    uint_t e2 = emb[(size_t)node * 64 + lane];
    float ax = __uint_as_float(e2 << 16);
    float ay = __uint_as_float(e2 & 0xFFFF0000u);
    for (int k0 = beg; k0 < end; k0 += 64) {
        int m = end - k0;
        if (m > 64) m = 64;
        int2 rec = recs[k0 + lane];
        int rx = rec.x, ry = rec.y;
        for (int k = 0; k < m; ++k) {
            int c = __builtin_amdgcn_readlane(rx, k);
            float v = __int_as_float(__builtin_amdgcn_readlane(ry, k));
            uint_t g = emb[(size_t)c * 64 + lane];
            ax += v * __uint_as_float(g << 16);
            ay += v * __uint_as_float(g & 0xFFFF0000u);
        }
    }
    float2* p = (float2*)&acc[(size_t)w * D + lane * 2];
    float2 r = *p;
    r.x += ax; r.y += ay;
    *p = r;
}

// layer-0 gather from the f32 inputs (set mode)
__global__ void k_sel0(const float* __restrict__ user_emb, const float* __restrict__ item_emb,
                       const int* __restrict__ users, const int* __restrict__ items,
                       float* __restrict__ acc) {
    int idx = blockIdx.x * blockDim.x + threadIdx.x;
    if (idx >= 2 * NSEL * D) return;
    int r = idx >> 7;
    int d = idx & (D - 1);
    const float* src = (r < NSEL) ? &user_emb[(size_t)users[r] * D]
                                  : &item_emb[(size_t)items[r - NSEL] * D];
    acc[idx] = src[d];
}

// gather selected rows from bf16 table, add into acc
__global__ void k_sel_bf16(const ushort_t* __restrict__ src,
                           const int* __restrict__ users, const int* __restrict__ items,
                           float* __restrict__ acc) {
    int idx = blockIdx.x * blockDim.x + threadIdx.x;
    if (idx >= 2 * NSEL * D) return;
    int r = idx >> 7;
    int d = idx & (D - 1);
    size_t node = (r < NSEL) ? (size_t)users[r] : (size_t)NUSERS + (size_t)items[r - NSEL];
    uint_t u = (uint_t)src[node * D + d] << 16;
    acc[idx] += __uint_as_float(u);
}

// one wave per output: gamma[i] = dot(accU[i], accI[i]) / 16
__global__ void k_dot(const float* __restrict__ acc, float* __restrict__ out) {
    int lane = threadIdx.x & 63;
    int w = (int)((blockIdx.x * blockDim.x + threadIdx.x) >> 6);
    if (w >= NSEL) return;
    const float* u = &acc[(size_t)w * D];
    const float* it = &acc[(size_t)(NSEL + w) * D];
    float s = u[lane] * it[lane] + u[lane + 64] * it[lane + 64];
    #pragma unroll
    for (int off = 32; off; off >>= 1) s += __shfl_down(s, off);
    if (lane == 0) out[w] = s * (1.0f / 16.0f);
}

extern "C" void kernel_launch(void* const* d_in, const int* in_sizes, int n_in,
                              void* d_out, int out_size, void* d_ws, size_t ws_size,
                              hipStream_t stream) {
    const float* user_emb = (const float*)d_in[0];
    const float* item_emb = (const float*)d_in[1];
    const float* edge_val = (const float*)d_in[2];
    const int*   edge_row = (const int*)d_in[3];
    const int*   edge_col = (const int*)d_in[4];
    const int*   users    = (const int*)d_in[5];
    const int*   items    = (const int*)d_in[6];
    float* out = (float*)d_out;

    const size_t tab = (size_t)NNODES * D;                     // elements
    ushort_t* bufA   = (ushort_t*)d_ws;                        // 38.4 MB bf16
    ushort_t* bufB   = bufA + tab;                             // 38.4 MB bf16
    float* accs      = (float*)(bufB + tab);                   // 2 MB f32
    int2*  recs      = (int2*)(accs + (size_t)2 * NSEL * D);   // 25.6 MB
    int2*  tmp       = recs + NEDGES;                          // 25.6 MB
    int*   mat       = (int*)(tmp + NEDGES);                   // 600 KB
    int*   row_start = mat + MATN;                             // 600 KB
    int*   bsums     = row_start + NNODES + 1;                 // 2.4 KB

    // ---- build CSR: atomic-free radix partition + per-bucket LDS sort ----
    k_p1<<<PBLK, 256, 0, stream>>>(edge_row, mat);
    k_blocksum<<<MB, 256, 0, stream>>>(mat, bsums, MATN);
    k_scanbsums<<<1, 1024, 0, stream>>>(bsums, MB);
    k_scan_inplace<<<MB, 256, 0, stream>>>(mat, bsums, MATN);
    k_p2<<<PBLK, 256, 0, stream>>>(edge_row, edge_col, edge_val, mat, tmp);
    k_p3<<<NBKT, 256, 0, stream>>>(tmp, mat, recs, row_start);

    // ---- embeddings ----
    k_init_bf16<<<2048, 256, 0, stream>>>((const float4*)user_emb, (const float4*)item_emb,
                                          (uint4*)bufA);
    k_sel0<<<(2 * NSEL * D) / 256, 256, 0, stream>>>(user_emb, item_emb, users, items, accs);

    // layer 1: full
    k_spmm_csr<<<(NNODES + 3) / 4, 256, 0, stream>>>((const uint_t*)bufA, (uint_t*)bufB,
                                                     row_start, recs);
    k_sel_bf16<<<(2 * NSEL * D) / 256, 256, 0, stream>>>(bufB, users, items, accs);
    // layer 2: full
    k_spmm_csr<<<(NNODES + 3) / 4, 256, 0, stream>>>((const uint_t*)bufB, (uint_t*)bufA,
                                                     row_start, recs);
    // layer 3 (selected rows only) fused with layer-2 k_sel
    k_spmm_sel<<<(2 * NSEL) / 4, 256, 0, stream>>>((const uint_t*)bufA, users, items,
                                                   row_start, recs, accs);

    k_dot<<<512, 256, 0, stream>>>(accs, out);
}

// Round 8
// 383.967 us; speedup vs baseline: 1.0280x; 1.0280x over previous
//
#include <hip/hip_runtime.h>

#define D 128
#define NUSERS 100000
#define NITEMS 50000
#define NNODES 150000
#define NEDGES 3200000
#define NSEL 2048
#define NBKT 586                 // ceil(150000 / 256) row-buckets of 256 rows
#define PBLK 256                 // partition blocks
#define EPB (NEDGES / PBLK)      // 12500 edges per partition block
#define MATN (NBKT * PBLK)       // 150016 (bucket-major count matrix)
#define MB ((MATN + 255) / 256)  // 586 scan blocks
#define BCAP 8192                // LDS bucket capacity in k_p3 (records)
#define INIT_BLKS 2048
#define SEL_BLKS ((2 * NSEL * D) / 256)   // 2048

typedef unsigned int uint_t;
typedef unsigned short ushort_t;
typedef unsigned long long ull_t;

__device__ inline uint_t bf16_rne(float f) {
    uint_t x = __float_as_uint(f);
    return (x + 0x7FFFu + ((x >> 16) & 1u)) >> 16;
}

// ---- generic block exclusive scan helper ----
__device__ inline int block_excl_scan(int v, int* lds, int nw) {
    int lane = threadIdx.x & 63;
    int wid = (int)(threadIdx.x >> 6);
    int x = v;
    #pragma unroll
    for (int off = 1; off < 64; off <<= 1) {
        int y = __shfl_up(x, off);
        if (lane >= off) x += y;
    }
    if (lane == 63) lds[wid] = x;
    __syncthreads();
    if (wid == 0) {
        int s = (lane < nw) ? lds[lane] : 0;
        #pragma unroll
        for (int off = 1; off < 16; off <<= 1) {
            int y = __shfl_up(s, off);
            if (lane >= off) s += y;
        }
        if (lane < nw) lds[lane] = s;
    }
    __syncthreads();
    int waveoff = (wid == 0) ? 0 : lds[wid - 1];
    return waveoff + x - v;
}

// Fused prologue: blocks [0,PBLK) = p1 bucket histogram; [PBLK,PBLK+INIT_BLKS) =
// bf16 table init; rest = sel0 gather. All independent.
__global__ void k_prologue(const int* __restrict__ row, int* __restrict__ mat,
                           const float4* __restrict__ u4, const float4* __restrict__ i4,
                           uint4* __restrict__ cur,
                           const float* __restrict__ user_emb,
                           const float* __restrict__ item_emb,
                           const int* __restrict__ users, const int* __restrict__ items,
                           float* __restrict__ acc) {
    __shared__ int h[NBKT];
    int blk = blockIdx.x;
    if (blk < PBLK) {
        // ---- p1: per-block LDS bucket histogram -> mat[bucket][block] ----
        for (int i = threadIdx.x; i < NBKT; i += 256) h[i] = 0;
        __syncthreads();
        int beg = blk * EPB, end = beg + EPB;
        for (int e = beg + threadIdx.x; e < end; e += 256)
            atomicAdd(&h[row[e] >> 8], 1);
        __syncthreads();
        for (int i = threadIdx.x; i < NBKT; i += 256)
            mat[i * PBLK + blk] = h[i];
    } else if (blk < PBLK + INIT_BLKS) {
        // ---- init: bf16 table = concat(user, item) ----
        size_t total8 = (size_t)NNODES * D / 8;
        size_t ub8 = (size_t)NUSERS * D / 8;
        size_t stride = (size_t)INIT_BLKS * 256;
        for (size_t i = (size_t)(blk - PBLK) * 256 + threadIdx.x; i < total8; i += stride) {
            const float4* src = (i < ub8) ? &u4[2 * i] : &i4[2 * (i - ub8)];
            float4 a = src[0], b = src[1];
            uint4 o;
            o.x = (bf16_rne(a.y) << 16) | bf16_rne(a.x);
            o.y = (bf16_rne(a.w) << 16) | bf16_rne(a.z);
            o.z = (bf16_rne(b.y) << 16) | bf16_rne(b.x);
            o.w = (bf16_rne(b.w) << 16) | bf16_rne(b.z);
            cur[i] = o;
        }
    } else {
        // ---- sel0: acc = layer-0 embeddings at selected rows (f32 inputs) ----
        int idx = (blk - PBLK - INIT_BLKS) * 256 + threadIdx.x;
        if (idx < 2 * NSEL * D) {
            int r = idx >> 7;
            int d = idx & (D - 1);
            const float* src = (r < NSEL) ? &user_emb[(size_t)users[r] * D]
                                          : &item_emb[(size_t)items[r - NSEL] * D];
            acc[idx] = src[d];
        }
    }
}

__global__ void k_blocksum(const int* __restrict__ src, int* __restrict__ bsums, int n) {
    int i = blockIdx.x * 256 + threadIdx.x;
    int v = (i < n) ? src[i] : 0;
    #pragma unroll
    for (int off = 32; off; off >>= 1) v += __shfl_down(v, off);
    __shared__ int lds[4];
    int lane = threadIdx.x & 63, wid = (int)(threadIdx.x >> 6);
    if (lane == 0) lds[wid] = v;
    __syncthreads();
    if (threadIdx.x == 0) bsums[blockIdx.x] = lds[0] + lds[1] + lds[2] + lds[3];
}

// merged scan: each block computes prefix of bsums[0..blk) itself, then local scan
__global__ void k_scan2(int* __restrict__ mat, const int* __restrict__ bsums, int n) {
    __shared__ int red[4];
    __shared__ int lds[4];
    int b = blockIdx.x;
    int lane = threadIdx.x & 63, wid = (int)(threadIdx.x >> 6);
    int s = 0;
    for (int j = threadIdx.x; j < b; j += 256) s += bsums[j];
    #pragma unroll
    for (int off = 32; off; off >>= 1) s += __shfl_down(s, off);
    if (lane == 0) red[wid] = s;
    __syncthreads();
    int base = red[0] + red[1] + red[2] + red[3];
    int i = b * 256 + threadIdx.x;
    int v = (i < n) ? mat[i] : 0;
    int ex = block_excl_scan(v, lds, 4);
    if (i < n) mat[i] = base + ex;
}

// P2: partition scatter using LDS cursors seeded from scanned mat (no global atomics)
__global__ void k_p2(const int* __restrict__ row, const int* __restrict__ col,
                     const float* __restrict__ val, const int* __restrict__ mat,
                     int2* __restrict__ tmp) {
    __shared__ int cur[NBKT];
    for (int i = threadIdx.x; i < NBKT; i += 256)
        cur[i] = mat[i * PBLK + blockIdx.x];
    __syncthreads();
    int beg = blockIdx.x * EPB, end = beg + EPB;
    for (int e = beg + threadIdx.x; e < end; e += 256) {
        int r = row[e];
        int b = r >> 8;
        int pos = atomicAdd(&cur[b], 1);
        int2 rc;
        rc.x = ((r & 255) << 24) | col[e];   // col < 2^24
        rc.y = __float_as_int(val[e]);
        tmp[pos] = rc;
    }
}

// P3: per-bucket exact CSR via LDS staging: one global read of tmp, LDS
// histogram + scan + scatter. Global-path fallback if bucket exceeds BCAP.
__global__ void k_p3(const int2* __restrict__ tmp, const int* __restrict__ mat,
                     int2* __restrict__ recs, int* __restrict__ row_start) {
    __shared__ int2 buf[BCAP];     // 64 KB
    __shared__ int h[256];
    __shared__ int lds[4];
    int b = blockIdx.x;
    int beg = mat[b * PBLK];
    int end = (b + 1 < NBKT) ? mat[(b + 1) * PBLK] : NEDGES;
    int n = end - beg;
    h[threadIdx.x] = 0;
    if (n <= BCAP) {
        for (int i = threadIdx.x; i < n; i += 256) buf[i] = tmp[beg + i];
        __syncthreads();
        for (int i = threadIdx.x; i < n; i += 256)
            atomicAdd(&h[((uint_t)buf[i].x) >> 24], 1);
        __syncthreads();
        int ex = block_excl_scan(h[threadIdx.x], lds, 4);
        int rowid = b * 256 + threadIdx.x;
        if (rowid < NNODES) row_start[rowid] = beg + ex;
        if (b == NBKT - 1 && threadIdx.x == 0) row_start[NNODES] = NEDGES;
        h[threadIdx.x] = ex;
        __syncthreads();
        for (int i = threadIdx.x; i < n; i += 256) {
            int2 rc = buf[i];
            int lr = ((uint_t)rc.x) >> 24;
            int pos = beg + atomicAdd(&h[lr], 1);
            int2 o;
            o.x = rc.x & 0xFFFFFF;
            o.y = rc.y;
            recs[pos] = o;
        }
    } else {
        __syncthreads();
        for (int e = beg + threadIdx.x; e < end; e += 256)
            atomicAdd(&h[((uint_t)tmp[e].x) >> 24], 1);
        __syncthreads();
        int ex = block_excl_scan(h[threadIdx.x], lds, 4);
        int rowid = b * 256 + threadIdx.x;
        if (rowid < NNODES) row_start[rowid] = beg + ex;
        if (b == NBKT - 1 && threadIdx.x == 0) row_start[NNODES] = NEDGES;
        h[threadIdx.x] = ex;
        __syncthreads();
        for (int e = beg + threadIdx.x; e < end; e += 256) {
            int2 rc = tmp[e];
            int lr = ((uint_t)rc.x) >> 24;
            int pos = beg + atomicAdd(&h[lr], 1);
            int2 o;
            o.x = rc.x & 0xFFFFFF;
            o.y = rc.y;
            recs[pos] = o;
        }
    }
}

// CSR SpMM on bf16 table: one wave per row, register accumulation, single
// non-atomic write. recs streamed nontemporally (don't pollute L2 — it caches
// table rows); output written nontemporally (no reuse this kernel).
__global__ void k_spmm_csr(const uint_t* __restrict__ emb, uint_t* __restrict__ outp,
                           const int* __restrict__ row_start,
                           const int2* __restrict__ recs) {
    int lane = threadIdx.x & 63;
    int w = (int)((blockIdx.x * blockDim.x + threadIdx.x) >> 6);
    if (w >= NNODES) return;
    int beg = __builtin_amdgcn_readfirstlane(row_start[w]);
    int end = __builtin_amdgcn_readfirstlane(row_start[w + 1]);
    const ull_t* rq = (const ull_t*)recs;
    float ax = 0.f, ay = 0.f;
    int e = beg;
    for (; e + 3 < end; e += 4) {
        ull_t q0 = __builtin_nontemporal_load(rq + e);
        ull_t q1 = __builtin_nontemporal_load(rq + e + 1);
        ull_t q2 = __builtin_nontemporal_load(rq + e + 2);
        ull_t q3 = __builtin_nontemporal_load(rq + e + 3);
        uint_t g0 = emb[(size_t)(uint_t)q0 * 64 + lane];
        uint_t g1 = emb[(size_t)(uint_t)q1 * 64 + lane];
        uint_t g2 = emb[(size_t)(uint_t)q2 * 64 + lane];
        uint_t g3 = emb[(size_t)(uint_t)q3 * 64 + lane];
        float v0 = __uint_as_float((uint_t)(q0 >> 32));
        float v1 = __uint_as_float((uint_t)(q1 >> 32));
        float v2 = __uint_as_float((uint_t)(q2 >> 32));
        float v3 = __uint_as_float((uint_t)(q3 >> 32));
        ax += v0 * __uint_as_float(g0 << 16) + v1 * __uint_as_float(g1 << 16)
            + v2 * __uint_as_float(g2 << 16) + v3 * __uint_as_float(g3 << 16);
        ay += v0 * __uint_as_float(g0 & 0xFFFF0000u) + v1 * __uint_as_float(g1 & 0xFFFF0000u)
            + v2 * __uint_as_float(g2 & 0xFFFF0000u) + v3 * __uint_as_float(g3 & 0xFFFF0000u);
    }
    for (; e < end; ++e) {
        ull_t q = __builtin_nontemporal_load(rq + e);
        float v = __uint_as_float((uint_t)(q >> 32));
        uint_t g = emb[(size_t)(uint_t)q * 64 + lane];
        ax += v * __uint_as_float(g << 16);
        ay += v * __uint_as_float(g & 0xFFFF0000u);
    }
    uint_t o = (bf16_rne(ay) << 16) | bf16_rne(ax);
    __builtin_nontemporal_store(o, &outp[(size_t)w * 64 + lane]);
}

// layer-3 SpMM at selected rows only, fused with acc += emb[node]
__global__ void k_spmm_sel(const uint_t* __restrict__ emb,
                           const int* __restrict__ users, const int* __restrict__ items,
                           const int* __restrict__ row_start,
                           const int2* __restrict__ recs,
                           float* __restrict__ acc) {
    int lane = threadIdx.x & 63;
    int w = (int)((blockIdx.x * blockDim.x + threadIdx.x) >> 6);
    if (w >= 2 * NSEL) return;
    int node = (w < NSEL) ? users[w] : NUSERS + items[w - NSEL];
    int beg = __builtin_amdgcn_readfirstlane(row_start[node]);
    int end = __builtin_amdgcn_readfirstlane(row_start[node + 1]);
    uint_t e2 = emb[(size_t)node * 64 + lane];
    float ax = __uint_as_float(e2 << 16);
    float ay = __uint_as_float(e2 & 0xFFFF0000u);
    for (int e = beg; e < end; ++e) {
        int2 r0 = recs[e];
        float v = __int_as_float(r0.y);
        uint_t g = emb[(size_t)r0.x * 64 + lane];
        ax += v * __uint_as_float(g << 16);
        ay += v * __uint_as_float(g & 0xFFFF0000u);
    }
    float2* p = (float2*)&acc[(size_t)w * D + lane * 2];
    float2 r = *p;
    r.x += ax; r.y += ay;
    *p = r;
}

// gather selected rows from bf16 table, add into acc
__global__ void k_sel_bf16(const ushort_t* __restrict__ src,
                           const int* __restrict__ users, const int* __restrict__ items,
                           float* __restrict__ acc) {
    int idx = blockIdx.x * blockDim.x + threadIdx.x;
    if (idx >= 2 * NSEL * D) return;
    int r = idx >> 7;
    int d = idx & (D - 1);
    size_t node = (r < NSEL) ? (size_t)users[r] : (size_t)NUSERS + (size_t)items[r - NSEL];
    uint_t u = (uint_t)src[node * D + d] << 16;
    acc[idx] += __uint_as_float(u);
}

// one wave per output: gamma[i] = dot(accU[i], accI[i]) / 16
__global__ void k_dot(const float* __restrict__ acc, float* __restrict__ out) {
    int lane = threadIdx.x & 63;
    int w = (int)((blockIdx.x * blockDim.x + threadIdx.x) >> 6);
    if (w >= NSEL) return;
    const float* u = &acc[(size_t)w * D];
    const float* it = &acc[(size_t)(NSEL + w) * D];
    float s = u[lane] * it[lane] + u[lane + 64] * it[lane + 64];
    #pragma unroll
    for (int off = 32; off; off >>= 1) s += __shfl_down(s, off);
    if (lane == 0) out[w] = s * (1.0f / 16.0f);
}

extern "C" void kernel_launch(void* const* d_in, const int* in_sizes, int n_in,
                              void* d_out, int out_size, void* d_ws, size_t ws_size,
                              hipStream_t stream) {
    const float* user_emb = (const float*)d_in[0];
    const float* item_emb = (const float*)d_in[1];
    const float* edge_val = (const float*)d_in[2];
    const int*   edge_row = (const int*)d_in[3];
    const int*   edge_col = (const int*)d_in[4];
    const int*   users    = (const int*)d_in[5];
    const int*   items    = (const int*)d_in[6];
    float* out = (float*)d_out;

    const size_t tab = (size_t)NNODES * D;                     // elements
    ushort_t* bufA   = (ushort_t*)d_ws;                        // 38.4 MB bf16
    ushort_t* bufB   = bufA + tab;                             // 38.4 MB bf16
    float* accs      = (float*)(bufB + tab);                   // 2 MB f32
    int2*  recs      = (int2*)(accs + (size_t)2 * NSEL * D);   // 25.6 MB
    int2*  tmp       = recs + NEDGES;                          // 25.6 MB
    int*   mat       = (int*)(tmp + NEDGES);                   // 600 KB
    int*   row_start = mat + MATN;                             // 600 KB
    int*   bsums     = row_start + NNODES + 1;                 // 2.4 KB

    // ---- prologue: p1 histogram + bf16 init + sel0 (fused, independent) ----
    k_prologue<<<PBLK + INIT_BLKS + SEL_BLKS, 256, 0, stream>>>(
        edge_row, mat, (const float4*)user_emb, (const float4*)item_emb,
        (uint4*)bufA, user_emb, item_emb, users, items, accs);

    // ---- CSR build: scan + partition + per-bucket LDS sort ----
    k_blocksum<<<MB, 256, 0, stream>>>(mat, bsums, MATN);
    k_scan2<<<MB, 256, 0, stream>>>(mat, bsums, MATN);
    k_p2<<<PBLK, 256, 0, stream>>>(edge_row, edge_col, edge_val, mat, tmp);
    k_p3<<<NBKT, 256, 0, stream>>>(tmp, mat, recs, row_start);

    // layer 1: full
    k_spmm_csr<<<(NNODES + 3) / 4, 256, 0, stream>>>((const uint_t*)bufA, (uint_t*)bufB,
                                                     row_start, recs);
    k_sel_bf16<<<SEL_BLKS, 256, 0, stream>>>(bufB, users, items, accs);
    // layer 2: full
    k_spmm_csr<<<(NNODES + 3) / 4, 256, 0, stream>>>((const uint_t*)bufB, (uint_t*)bufA,
                                                     row_start, recs);
    // layer 3 (selected rows only) fused with layer-2 k_sel
    k_spmm_sel<<<(2 * NSEL) / 4, 256, 0, stream>>>((const uint_t*)bufA, users, items,
                                                   row_start, recs, accs);

    k_dot<<<512, 256, 0, stream>>>(accs, out);
}

// Round 9
// 329.911 us; speedup vs baseline: 1.1965x; 1.1639x over previous
//
#include <hip/hip_runtime.h>

#define D 128
#define NUSERS 100000
#define NITEMS 50000
#define NNODES 150000
#define NEDGES 3200000
#define NSEL 2048
#define NBKT 586                 // ceil(150000 / 256) row-buckets of 256 rows
#define PBLK 256                 // partition blocks
#define EPB (NEDGES / PBLK)      // 12500 edges per partition block
#define MATN (NBKT * PBLK)       // 150016 (bucket-major count matrix)
#define MB ((MATN + 255) / 256)  // 586 scan blocks
#define BCAP 8192                // LDS bucket capacity in k_p3 (records)
#define INIT_BLKS 2048
#define SEL_BLKS ((2 * NSEL * D) / 256)   // 2048
#define FLG_BLKS ((NNODES + 255) / 256)   // 586
#define COLMASK 0x3FFFFu

typedef unsigned int uint_t;
typedef unsigned short ushort_t;

__device__ inline uint_t bf16_rne(float f) {
    uint_t x = __float_as_uint(f);
    return (x + 0x7FFFu + ((x >> 16) & 1u)) >> 16;
}

// ---- generic block exclusive scan helper ----
__device__ inline int block_excl_scan(int v, int* lds, int nw) {
    int lane = threadIdx.x & 63;
    int wid = (int)(threadIdx.x >> 6);
    int x = v;
    #pragma unroll
    for (int off = 1; off < 64; off <<= 1) {
        int y = __shfl_up(x, off);
        if (lane >= off) x += y;
    }
    if (lane == 63) lds[wid] = x;
    __syncthreads();
    if (wid == 0) {
        int s = (lane < nw) ? lds[lane] : 0;
        #pragma unroll
        for (int off = 1; off < 16; off <<= 1) {
            int y = __shfl_up(s, off);
            if (lane >= off) s += y;
        }
        if (lane < nw) lds[lane] = s;
    }
    __syncthreads();
    int waveoff = (wid == 0) ? 0 : lds[wid - 1];
    return waveoff + x - v;
}

// Fused prologue: [0,PBLK) = p1 histogram; [PBLK,+INIT_BLKS) = bf16 table init;
// [+SEL_BLKS) = sel0 gather; rest = zero flags. All independent.
__global__ void k_prologue(const int* __restrict__ row, int* __restrict__ mat,
                           const float4* __restrict__ u4, const float4* __restrict__ i4,
                           uint4* __restrict__ cur,
                           const float* __restrict__ user_emb,
                           const float* __restrict__ item_emb,
                           const int* __restrict__ users, const int* __restrict__ items,
                           float* __restrict__ acc, int* __restrict__ flags) {
    __shared__ int h[NBKT];
    int blk = blockIdx.x;
    if (blk < PBLK) {
        for (int i = threadIdx.x; i < NBKT; i += 256) h[i] = 0;
        __syncthreads();
        int beg = blk * EPB, end = beg + EPB;
        for (int e = beg + threadIdx.x; e < end; e += 256)
            atomicAdd(&h[row[e] >> 8], 1);
        __syncthreads();
        for (int i = threadIdx.x; i < NBKT; i += 256)
            mat[i * PBLK + blk] = h[i];
    } else if (blk < PBLK + INIT_BLKS) {
        size_t total8 = (size_t)NNODES * D / 8;
        size_t ub8 = (size_t)NUSERS * D / 8;
        size_t stride = (size_t)INIT_BLKS * 256;
        for (size_t i = (size_t)(blk - PBLK) * 256 + threadIdx.x; i < total8; i += stride) {
            const float4* src = (i < ub8) ? &u4[2 * i] : &i4[2 * (i - ub8)];
            float4 a = src[0], b = src[1];
            uint4 o;
            o.x = (bf16_rne(a.y) << 16) | bf16_rne(a.x);
            o.y = (bf16_rne(a.w) << 16) | bf16_rne(a.z);
            o.z = (bf16_rne(b.y) << 16) | bf16_rne(b.x);
            o.w = (bf16_rne(b.w) << 16) | bf16_rne(b.z);
            cur[i] = o;
        }
    } else if (blk < PBLK + INIT_BLKS + SEL_BLKS) {
        int idx = (blk - PBLK - INIT_BLKS) * 256 + threadIdx.x;
        if (idx < 2 * NSEL * D) {
            int r = idx >> 7;
            int d = idx & (D - 1);
            const float* src = (r < NSEL) ? &user_emb[(size_t)users[r] * D]
                                          : &item_emb[(size_t)items[r - NSEL] * D];
            acc[idx] = src[d];
        }
    } else {
        int i = (blk - PBLK - INIT_BLKS - SEL_BLKS) * 256 + threadIdx.x;
        if (i < NNODES) flags[i] = 0;
    }
}

__global__ void k_blocksum(const int* __restrict__ src, int* __restrict__ bsums, int n) {
    int i = blockIdx.x * 256 + threadIdx.x;
    int v = (i < n) ? src[i] : 0;
    #pragma unroll
    for (int off = 32; off; off >>= 1) v += __shfl_down(v, off);
    __shared__ int lds[4];
    int lane = threadIdx.x & 63, wid = (int)(threadIdx.x >> 6);
    if (lane == 0) lds[wid] = v;
    __syncthreads();
    if (threadIdx.x == 0) bsums[blockIdx.x] = lds[0] + lds[1] + lds[2] + lds[3];
}

// merged scan: each block computes prefix of bsums[0..blk) itself, then local scan
__global__ void k_scan2(int* __restrict__ mat, const int* __restrict__ bsums, int n) {
    __shared__ int red[4];
    __shared__ int lds[4];
    int b = blockIdx.x;
    int lane = threadIdx.x & 63, wid = (int)(threadIdx.x >> 6);
    int s = 0;
    for (int j = threadIdx.x; j < b; j += 256) s += bsums[j];
    #pragma unroll
    for (int off = 32; off; off >>= 1) s += __shfl_down(s, off);
    if (lane == 0) red[wid] = s;
    __syncthreads();
    int base = red[0] + red[1] + red[2] + red[3];
    int i = b * 256 + threadIdx.x;
    int v = (i < n) ? mat[i] : 0;
    int ex = block_excl_scan(v, lds, 4);
    if (i < n) mat[i] = base + ex;
}

// P2: partition scatter; tmp.x = row-in-bucket, tmp.y = packed (val14|col18)
__global__ void k_p2(const int* __restrict__ row, const int* __restrict__ col,
                     const float* __restrict__ val, const int* __restrict__ mat,
                     int2* __restrict__ tmp) {
    __shared__ int cur[NBKT];
    for (int i = threadIdx.x; i < NBKT; i += 256)
        cur[i] = mat[i * PBLK + blockIdx.x];
    __syncthreads();
    int beg = blockIdx.x * EPB, end = beg + EPB;
    for (int e = beg + threadIdx.x; e < end; e += 256) {
        int r = row[e];
        int b = r >> 8;
        int pos = atomicAdd(&cur[b], 1);
        int q = (int)(val[e] * 16384.f + 0.5f);
        if (q > 16383) q = 16383;
        int2 rc;
        rc.x = r & 255;
        rc.y = (int)(((uint_t)q << 18) | (uint_t)col[e]);
        tmp[pos] = rc;
    }
}

// P3: per-bucket exact CSR via LDS staging; writes packed 4B records
__global__ void k_p3(const int2* __restrict__ tmp, const int* __restrict__ mat,
                     uint_t* __restrict__ recs, int* __restrict__ row_start) {
    __shared__ int2 buf[BCAP];     // 64 KB
    __shared__ int h[256];
    __shared__ int lds[4];
    int b = blockIdx.x;
    int beg = mat[b * PBLK];
    int end = (b + 1 < NBKT) ? mat[(b + 1) * PBLK] : NEDGES;
    int n = end - beg;
    h[threadIdx.x] = 0;
    if (n <= BCAP) {
        for (int i = threadIdx.x; i < n; i += 256) buf[i] = tmp[beg + i];
        __syncthreads();
        for (int i = threadIdx.x; i < n; i += 256)
            atomicAdd(&h[buf[i].x], 1);
        __syncthreads();
        int ex = block_excl_scan(h[threadIdx.x], lds, 4);
        int rowid = b * 256 + threadIdx.x;
        if (rowid < NNODES) row_start[rowid] = beg + ex;
        if (b == NBKT - 1 && threadIdx.x == 0) row_start[NNODES] = NEDGES;
        h[threadIdx.x] = ex;
        __syncthreads();
        for (int i = threadIdx.x; i < n; i += 256) {
            int2 rc = buf[i];
            int pos = beg + atomicAdd(&h[rc.x], 1);
            recs[pos] = (uint_t)rc.y;
        }
    } else {
        __syncthreads();
        for (int e = beg + threadIdx.x; e < end; e += 256)
            atomicAdd(&h[tmp[e].x], 1);
        __syncthreads();
        int ex = block_excl_scan(h[threadIdx.x], lds, 4);
        int rowid = b * 256 + threadIdx.x;
        if (rowid < NNODES) row_start[rowid] = beg + ex;
        if (b == NBKT - 1 && threadIdx.x == 0) row_start[NNODES] = NEDGES;
        h[threadIdx.x] = ex;
        __syncthreads();
        for (int e = beg + threadIdx.x; e < end; e += 256) {
            int2 rc = tmp[e];
            int pos = beg + atomicAdd(&h[rc.x], 1);
            recs[pos] = (uint_t)rc.y;
        }
    }
}

// mark rows of layer-2 output actually consumed by layer-3/sel: selected nodes
// and all cols reachable from selected rows' edges
__global__ void k_mark(const int* __restrict__ users, const int* __restrict__ items,
                       const int* __restrict__ row_start, const uint_t* __restrict__ recs,
                       int* __restrict__ flags) {
    int lane = threadIdx.x & 63;
    int w = (int)((blockIdx.x * blockDim.x + threadIdx.x) >> 6);
    if (w >= 2 * NSEL) return;
    int node = (w < NSEL) ? users[w] : NUSERS + items[w - NSEL];
    int beg = __builtin_amdgcn_readfirstlane(row_start[node]);
    int end = __builtin_amdgcn_readfirstlane(row_start[node + 1]);
    if (lane == 0) flags[node] = 1;
    for (int e = beg + lane; e < end; e += 64)
        flags[recs[e] & COLMASK] = 1;
}

// CSR SpMM on bf16 table: one wave per row, register accumulation, single
// non-atomic write. use_flags: skip rows whose output is never consumed.
__global__ void k_spmm_csr(const uint_t* __restrict__ emb, uint_t* __restrict__ outp,
                           const int* __restrict__ row_start,
                           const uint_t* __restrict__ recs,
                           const int* __restrict__ flags, int use_flags) {
    int lane = threadIdx.x & 63;
    int w = (int)((blockIdx.x * blockDim.x + threadIdx.x) >> 6);
    if (w >= NNODES) return;
    if (use_flags && __builtin_amdgcn_readfirstlane(flags[w]) == 0) return;
    int beg = __builtin_amdgcn_readfirstlane(row_start[w]);
    int end = __builtin_amdgcn_readfirstlane(row_start[w + 1]);
    float ax = 0.f, ay = 0.f;
    int e = beg;
    for (; e + 3 < end; e += 4) {
        uint_t q0 = recs[e], q1 = recs[e + 1], q2 = recs[e + 2], q3 = recs[e + 3];
        uint_t g0 = emb[(size_t)(q0 & COLMASK) * 64 + lane];
        uint_t g1 = emb[(size_t)(q1 & COLMASK) * 64 + lane];
        uint_t g2 = emb[(size_t)(q2 & COLMASK) * 64 + lane];
        uint_t g3 = emb[(size_t)(q3 & COLMASK) * 64 + lane];
        float v0 = (float)(q0 >> 18) * (1.f / 16384.f);
        float v1 = (float)(q1 >> 18) * (1.f / 16384.f);
        float v2 = (float)(q2 >> 18) * (1.f / 16384.f);
        float v3 = (float)(q3 >> 18) * (1.f / 16384.f);
        ax += v0 * __uint_as_float(g0 << 16) + v1 * __uint_as_float(g1 << 16)
            + v2 * __uint_as_float(g2 << 16) + v3 * __uint_as_float(g3 << 16);
        ay += v0 * __uint_as_float(g0 & 0xFFFF0000u) + v1 * __uint_as_float(g1 & 0xFFFF0000u)
            + v2 * __uint_as_float(g2 & 0xFFFF0000u) + v3 * __uint_as_float(g3 & 0xFFFF0000u);
    }
    for (; e < end; ++e) {
        uint_t q = recs[e];
        float v = (float)(q >> 18) * (1.f / 16384.f);
        uint_t g = emb[(size_t)(q & COLMASK) * 64 + lane];
        ax += v * __uint_as_float(g << 16);
        ay += v * __uint_as_float(g & 0xFFFF0000u);
    }
    outp[(size_t)w * 64 + lane] = (bf16_rne(ay) << 16) | bf16_rne(ax);
}

// layer-3 SpMM at selected rows only, fused with acc += emb[node]
__global__ void k_spmm_sel(const uint_t* __restrict__ emb,
                           const int* __restrict__ users, const int* __restrict__ items,
                           const int* __restrict__ row_start,
                           const uint_t* __restrict__ recs,
                           float* __restrict__ acc) {
    int lane = threadIdx.x & 63;
    int w = (int)((blockIdx.x * blockDim.x + threadIdx.x) >> 6);
    if (w >= 2 * NSEL) return;
    int node = (w < NSEL) ? users[w] : NUSERS + items[w - NSEL];
    int beg = __builtin_amdgcn_readfirstlane(row_start[node]);
    int end = __builtin_amdgcn_readfirstlane(row_start[node + 1]);
    uint_t e2 = emb[(size_t)node * 64 + lane];
    float ax = __uint_as_float(e2 << 16);
    float ay = __uint_as_float(e2 & 0xFFFF0000u);
    for (int e = beg; e < end; ++e) {
        uint_t q = recs[e];
        float v = (float)(q >> 18) * (1.f / 16384.f);
        uint_t g = emb[(size_t)(q & COLMASK) * 64 + lane];
        ax += v * __uint_as_float(g << 16);
        ay += v * __uint_as_float(g & 0xFFFF0000u);
    }
    float2* p = (float2*)&acc[(size_t)w * D + lane * 2];
    float2 r = *p;
    r.x += ax; r.y += ay;
    *p = r;
}

// gather selected rows from bf16 table, add into acc
__global__ void k_sel_bf16(const ushort_t* __restrict__ src,
                           const int* __restrict__ users, const int* __restrict__ items,
                           float* __restrict__ acc) {
    int idx = blockIdx.x * blockDim.x + threadIdx.x;
    if (idx >= 2 * NSEL * D) return;
    int r = idx >> 7;
    int d = idx & (D - 1);
    size_t node = (r < NSEL) ? (size_t)users[r] : (size_t)NUSERS + (size_t)items[r - NSEL];
    uint_t u = (uint_t)src[node * D + d] << 16;
    acc[idx] += __uint_as_float(u);
}

// one wave per output: gamma[i] = dot(accU[i], accI[i]) / 16
__global__ void k_dot(const float* __restrict__ acc, float* __restrict__ out) {
    int lane = threadIdx.x & 63;
    int w = (int)((blockIdx.x * blockDim.x + threadIdx.x) >> 6);
    if (w >= NSEL) return;
    const float* u = &acc[(size_t)w * D];
    const float* it = &acc[(size_t)(NSEL + w) * D];
    float s = u[lane] * it[lane] + u[lane + 64] * it[lane + 64];
    #pragma unroll
    for (int off = 32; off; off >>= 1) s += __shfl_down(s, off);
    if (lane == 0) out[w] = s * (1.0f / 16.0f);
}

extern "C" void kernel_launch(void* const* d_in, const int* in_sizes, int n_in,
                              void* d_out, int out_size, void* d_ws, size_t ws_size,
                              hipStream_t stream) {
    const float* user_emb = (const float*)d_in[0];
    const float* item_emb = (const float*)d_in[1];
    const float* edge_val = (const float*)d_in[2];
    const int*   edge_row = (const int*)d_in[3];
    const int*   edge_col = (const int*)d_in[4];
    const int*   users    = (const int*)d_in[5];
    const int*   items    = (const int*)d_in[6];
    float* out = (float*)d_out;

    const size_t tab = (size_t)NNODES * D;                     // elements
    ushort_t* bufA   = (ushort_t*)d_ws;                        // 38.4 MB bf16
    ushort_t* bufB   = bufA + tab;                             // 38.4 MB bf16
    float* accs      = (float*)(bufB + tab);                   // 2 MB f32
    uint_t* recs     = (uint_t*)(accs + (size_t)2 * NSEL * D); // 12.8 MB packed
    int2*  tmp       = (int2*)(recs + NEDGES);                 // 25.6 MB
    int*   mat       = (int*)(tmp + NEDGES);                   // 600 KB
    int*   row_start = mat + MATN;                             // 600 KB
    int*   flags     = row_start + NNODES + 1;                 // 600 KB
    int*   bsums     = flags + NNODES;                         // 2.4 KB

    // ---- prologue: p1 histogram + bf16 init + sel0 + zero flags ----
    k_prologue<<<PBLK + INIT_BLKS + SEL_BLKS + FLG_BLKS, 256, 0, stream>>>(
        edge_row, mat, (const float4*)user_emb, (const float4*)item_emb,
        (uint4*)bufA, user_emb, item_emb, users, items, accs, flags);

    // ---- CSR build ----
    k_blocksum<<<MB, 256, 0, stream>>>(mat, bsums, MATN);
    k_scan2<<<MB, 256, 0, stream>>>(mat, bsums, MATN);
    k_p2<<<PBLK, 256, 0, stream>>>(edge_row, edge_col, edge_val, mat, tmp);
    k_p3<<<NBKT, 256, 0, stream>>>(tmp, mat, recs, row_start);
    k_mark<<<(2 * NSEL) / 4, 256, 0, stream>>>(users, items, row_start, recs, flags);

    // layer 1: full
    k_spmm_csr<<<(NNODES + 3) / 4, 256, 0, stream>>>((const uint_t*)bufA, (uint_t*)bufB,
                                                     row_start, recs, flags, 0);
    k_sel_bf16<<<SEL_BLKS, 256, 0, stream>>>(bufB, users, items, accs);
    // layer 2: only rows consumed downstream (~44%)
    k_spmm_csr<<<(NNODES + 3) / 4, 256, 0, stream>>>((const uint_t*)bufB, (uint_t*)bufA,
                                                     row_start, recs, flags, 1);
    // layer 3 (selected rows only) fused with layer-2 k_sel
    k_spmm_sel<<<(2 * NSEL) / 4, 256, 0, stream>>>((const uint_t*)bufA, users, items,
                                                   row_start, recs, accs);

    k_dot<<<512, 256, 0, stream>>>(accs, out);
}